// Round 7
// baseline (26.609 us; speedup 1.0000x reference)
//
#include <hip/hip_runtime.h>
#include <math.h>

namespace {
constexpr int W = 256, H = 256, TILE = 16, NTX = 16, NT = 256, K = 256;
constexpr float FX = 200.0f, FY = 200.0f, NEARP = 0.3f, MAGIC = 1.2f;
constexpr float LP = 0.3f / (FX * FX);
constexpr float HALF_W = W * MAGIC / 2.0f / FX;   // 0.768
constexpr float HALF_H = H * MAGIC / 2.0f / FY;   // 0.768
constexpr float THDIAG = 0.05656854249492381f;    // 0.5*sqrt((TILE/FX)^2+(TILE/FY)^2)
constexpr int CAP = 1024;        // cnt ~ 157 +- 12.5; 1024 = +70 sigma
constexpr int N_PAD = 10240;
constexpr int BT = 1024;
constexpr int NB_MAX = 64;
constexpr int SEG = 256;
// ws layout
constexpr size_t A_OFF  = 0;                                   // pa: (mx,my,radius,z)
constexpr size_t B_OFF  = A_OFF + (size_t)N_PAD * 16;          // pb: (a',nb',c',lopa)
constexpr size_t C_OFF  = B_OFF + (size_t)N_PAD * 16;          // pc: (cr,cg,cb,-)
constexpr size_t SL_OFF = C_OFF + (size_t)N_PAD * 16;          // seglen[NT*NB_MAX]
constexpr size_t LD_OFF = SL_OFF + (size_t)NT * NB_MAX * 4;    // listd
constexpr size_t LZ_OFF = LD_OFF + (size_t)NT * NB_MAX * SEG * 8;  // listz
constexpr size_t WS_FULL = LZ_OFF + (size_t)NT * NB_MAX * SEG * 8;
}

__device__ inline float rlane(float v, int l) {
  return __int_as_float(__builtin_amdgcn_readlane(__float_as_int(v), l));
}

struct Pre { float mx, my, z, a, b, c, radius; };

__device__ inline Pre preprocess(int g, const float* __restrict__ pos,
                                 const float* __restrict__ quat,
                                 const float* __restrict__ scl,
                                 const float* __restrict__ w2cr,
                                 const float* __restrict__ w2ct) {
  float p0 = pos[3*g+0], p1 = pos[3*g+1], p2 = pos[3*g+2];
  float qw = quat[4*g+0], qx = quat[4*g+1], qy = quat[4*g+2], qz = quat[4*g+3];
  float inv = 1.0f / sqrtf(qw*qw + qx*qx + qy*qy + qz*qz);
  qw *= inv; qx *= inv; qy *= inv; qz *= inv;
  float r00 = 1.f-2.f*(qy*qy+qz*qz), r01 = 2.f*(qx*qy-qw*qz), r02 = 2.f*(qx*qz+qw*qy);
  float r10 = 2.f*(qx*qy+qw*qz), r11 = 1.f-2.f*(qx*qx+qz*qz), r12 = 2.f*(qy*qz-qw*qx);
  float r20 = 2.f*(qx*qz-qw*qy), r21 = 2.f*(qy*qz+qw*qx), r22 = 1.f-2.f*(qx*qx+qy*qy);
  float e0 = expf(scl[3*g+0]); float s0 = e0*e0;
  float e1 = expf(scl[3*g+1]); float s1 = e1*e1;
  float e2 = expf(scl[3*g+2]); float s2 = e2*e2;
  float C00 = r00*r00*s0 + r01*r01*s1 + r02*r02*s2;
  float C01 = r00*r10*s0 + r01*r11*s1 + r02*r12*s2;
  float C02 = r00*r20*s0 + r01*r21*s1 + r02*r22*s2;
  float C11 = r10*r10*s0 + r11*r11*s1 + r12*r12*s2;
  float C12 = r10*r20*s0 + r11*r21*s1 + r12*r22*s2;
  float C22 = r20*r20*s0 + r21*r21*s1 + r22*r22*s2;
  float w00=w2cr[0],w01=w2cr[1],w02=w2cr[2];
  float w10=w2cr[3],w11=w2cr[4],w12=w2cr[5];
  float w20=w2cr[6],w21=w2cr[7],w22=w2cr[8];
  float x = w00*p0 + w01*p1 + w02*p2 + w2ct[0];
  float y = w10*p0 + w11*p1 + w12*p2 + w2ct[1];
  float z = w20*p0 + w21*p1 + w22*p2 + w2ct[2];
  float m00 = w00*C00 + w01*C01 + w02*C02;
  float m01 = w00*C01 + w01*C11 + w02*C12;
  float m02 = w00*C02 + w01*C12 + w02*C22;
  float m10 = w10*C00 + w11*C01 + w12*C02;
  float m11 = w10*C01 + w11*C11 + w12*C12;
  float m12 = w10*C02 + w11*C12 + w12*C22;
  float m20 = w20*C00 + w21*C01 + w22*C02;
  float m21 = w20*C01 + w21*C11 + w22*C12;
  float m22 = w20*C02 + w21*C12 + w22*C22;
  float v00 = m00*w00 + m01*w01 + m02*w02;
  float v01 = m00*w10 + m01*w11 + m02*w12;
  float v02 = m00*w20 + m01*w21 + m02*w22;
  float v10 = m10*w00 + m11*w01 + m12*w02;
  float v11 = m10*w10 + m11*w11 + m12*w12;
  float v12 = m10*w20 + m11*w21 + m12*w22;
  float v20 = m20*w00 + m21*w01 + m22*w02;
  float v21 = m20*w10 + m21*w11 + m22*w12;
  float v22 = m20*w20 + m21*w21 + m22*w22;
  float zc = fmaxf(z, 1e-6f);
  float iz = 1.0f / zc;
  float mx = x * iz, my = y * iz;
  float iz2 = iz * iz;
  float jx = -x * iz2, jy = -y * iz2;
  float a00 = iz*v00 + jx*v20, a01 = iz*v01 + jx*v21, a02 = iz*v02 + jx*v22;
  float a10 = iz*v10 + jy*v20, a11 = iz*v11 + jy*v21, a12 = iz*v12 + jy*v22;
  float A  = a00*iz + a02*jx + LP;
  float Bv = a01*iz + a02*jy;
  float Cv = a11*iz + a12*jy + LP;
  float mid = 0.5f*(A + Cv);
  float hh  = 0.5f*(A - Cv);
  float disc = fmaxf(hh*hh + Bv*Bv, 0.0f);
  float smax = sqrtf(fmaxf(mid + sqrtf(disc), 1e-12f));
  bool infr = (z > NEARP) && (fabsf(mx) < HALF_W) && (fabsf(my) < HALF_H);
  Pre r;
  r.mx = mx; r.my = my; r.z = z; r.a = A; r.b = Bv; r.c = Cv;
  r.radius = infr ? (3.0f * smax + THDIAG) : -1.0f;
  return r;
}

// ---- preprocess + segmented binning ----

template <bool BIN>
__global__ __launch_bounds__(256)
void pre_bin(const float* __restrict__ pos, const float* __restrict__ rgb,
             const float* __restrict__ opac, const float* __restrict__ quat,
             const float* __restrict__ scl, const float* __restrict__ w2cr,
             const float* __restrict__ w2ct,
             float4* __restrict__ pa, float4* __restrict__ pb,
             float4* __restrict__ pc, int* __restrict__ seglen,
             unsigned long long* __restrict__ listd,
             unsigned long long* __restrict__ listz, int n) {
  __shared__ int s_tc[NT];
  const int tid = (int)threadIdx.x;
  const int blk = (int)blockIdx.x;
  if (BIN) {
    if (tid < NT) s_tc[tid] = 0;
    __syncthreads();
  }
  const int g = blk * 256 + tid;
  if (g < n) {
    Pre p = preprocess(g, pos, quat, scl, w2cr, w2ct);
    float det = fmaxf(p.a * p.c - p.b * p.b, 1e-12f);
    float ivd = 1.0f / det;
    float lopa = -__logf(1.0f + __expf(-opac[g]));   // log(sigmoid(o))
    pa[g] = make_float4(p.mx, p.my, p.radius, p.z);
    pb[g] = make_float4(p.a * ivd, -2.0f * p.b * ivd, p.c * ivd, lopa);
    pc[g] = make_float4(1.0f / (1.0f + __expf(-rgb[3*g+0])),
                        1.0f / (1.0f + __expf(-rgb[3*g+1])),
                        1.0f / (1.0f + __expf(-rgb[3*g+2])), 0.0f);
    if (BIN && p.radius >= 0.0f) {
      float r = p.radius;
      int txlo = max(0,     (int)floorf(((p.mx - r) * FX + 120.0f) * 0.0625f));
      int txhi = min(NTX-1, (int)ceilf (((p.mx + r) * FX + 120.0f) * 0.0625f));
      int tylo = max(0,     (int)floorf(((p.my - r) * FY + 120.0f) * 0.0625f));
      int tyhi = min(NTX-1, (int)ceilf (((p.my + r) * FY + 120.0f) * 0.0625f));
      unsigned long long gbits = (unsigned int)g;
      for (int ty = tylo; ty <= tyhi; ++ty) {
        float cy = (ty * TILE + TILE * 0.5f - H * 0.5f) / FY;
        float ddy = cy - p.my;
        for (int tx = txlo; tx <= txhi; ++tx) {
          float cx = (tx * TILE + TILE * 0.5f - W * 0.5f) / FX;
          float ddx = cx - p.mx;
          float dist = sqrtf(ddx * ddx + ddy * ddy);   // exact reference predicate
          if (dist <= r) {
            int t = ty * NTX + tx;
            int slot = atomicAdd(&s_tc[t], 1);   // < 256 per block => slot < SEG
            size_t idx = ((size_t)t * NB_MAX + blk) * SEG + slot;
            listd[idx] = ((unsigned long long)__float_as_uint(dist) << 32) | gbits;
            listz[idx] = ((unsigned long long)__float_as_uint(p.z)  << 32) | gbits;
          }
        }
      }
    }
  }
  if (BIN) {
    __syncthreads();
    if (tid < NT) seglen[(size_t)tid * NB_MAX + blk] = s_tc[tid];
  }
}

// ---- hybrid bitonic (rare cnt>K path only), M <= 1024, BT threads ----

__device__ inline void hsort1(unsigned long long* key, int M) {
  const int tid = (int)threadIdx.x;
  __syncthreads();
  unsigned long long e = (tid < M) ? key[tid] : ~0ull;
  for (int k = 2; k <= M; k <<= 1) {
    for (int j = k >> 1; j >= 64; j >>= 1) {
      __syncthreads();
      if (tid < M) key[tid] = e;
      __syncthreads();
      if (tid < M) {
        unsigned long long p = key[tid ^ j];
        bool takeMin = (((tid & j) == 0) == ((tid & k) == 0));
        e = ((p < e) == takeMin) ? p : e;   // keys unique
      }
    }
    int j0 = ((k >> 1) < 32) ? (k >> 1) : 32;
    for (int j = j0; j >= 1; j >>= 1) {
      unsigned long long p = __shfl_xor(e, j, 64);
      bool takeMin = (((tid & j) == 0) == ((tid & k) == 0));
      e = ((p < e) == takeMin) ? p : e;
    }
  }
  __syncthreads();
  if (tid < M) key[tid] = e;
  __syncthreads();
}

// ---- shared tail: rank z-sort -> scatter -> readlane blend -> combine ----

__device__ inline void tail_blend(
    const float4* __restrict__ pa, const float4* __restrict__ pb,
    const float4* __restrict__ pc, float* __restrict__ out,
    unsigned long long* s_zkey, int* s_rank,
    float4* s_q0, float4* s_q1, float* s_q2, float4* s_part,
    int cnt2, int tx, int ty) {
  const int tid = (int)threadIdx.x;
  // rank sort by (z, idx): 4 quarter-counts per element, unique keys
  {
    const int e = tid & 255;
    const int q = tid >> 8;
    if (e < cnt2) {
      unsigned long long mykey = s_zkey[e];
      int jlo = q * 64;
      int jhi = min(cnt2, jlo + 64);
      int partial = 0;
      for (int j = jlo; j < jhi; ++j)
        partial += (s_zkey[j] < mykey) ? 1 : 0;
      if (partial) atomicAdd(&s_rank[e], partial);
    }
  }
  __syncthreads();
  // scatter blend-ready params to rank position
  if (tid < cnt2) {
    int g = (int)(s_zkey[tid] & 0xffffffffu);
    int r = s_rank[tid];
    float4 A = pa[g], B = pb[g], C = pc[g];
    s_q0[r] = make_float4(A.x, A.y, B.x, B.y);   // mx, my, a', nb'
    s_q1[r] = make_float4(B.z, B.w, C.x, C.y);   // c', lopa, cr, cg
    s_q2[r] = C.z;                               // cb
  }
  __syncthreads();

  const int p    = tid & 255;
  const int q    = tid >> 8;
  const int L    = tid & 63;
  const int prow = p / TILE, pcol = p % TILE;
  const float u = ((float)(tx * TILE + pcol) + 0.5f - W * 0.5f) / FX;
  const float v = ((float)(ty * TILE + prow) + 0.5f - H * 0.5f) / FY;
  const int chunk = (cnt2 + 3) >> 2;
  const int k0 = q * chunk;
  const int k1 = min(cnt2, k0 + chunk);
  const int nk = max(0, k1 - k0);

  // stage: lane L of each wave holds params of entry k0+L in VGPRs
  int e2 = k0 + L;                       // <= 192+63 = 255, in-bounds
  bool val = (L < nk);
  float4 q0 = val ? s_q0[e2] : make_float4(0.f, 0.f, 0.f, 0.f);
  float4 q1 = val ? s_q1[e2] : make_float4(1e30f, -1e30f, 0.f, 0.f);
  float  qb = val ? s_q2[e2] : 0.f;

  float T = 1.0f, accr = 0.0f, accg = 0.0f, accb = 0.0f;
  for (int k2 = 0; k2 < nk; ++k2) {
    float mx  = rlane(q0.x, k2);
    float my  = rlane(q0.y, k2);
    float ap  = rlane(q0.z, k2);
    float nb2 = rlane(q0.w, k2);
    float cp  = rlane(q1.x, k2);
    float dx = u - mx;
    float dy = v - my;
    float maha = fmaf(cp * dx, dx, fmaf(nb2 * dx, dy, (ap * dy) * dy));
    // skip if alpha < 1e-5: total output perturbation <= 256*1e-5 = 2.6e-3
    if (maha < 23.0f) {
      float lopa = rlane(q1.y, k2);
      float cr   = rlane(q1.z, k2);
      float cg   = rlane(q1.w, k2);
      float cb   = rlane(qb,  k2);
      float alpha = fminf(__expf(fmaf(-0.5f, maha, lopa)), 0.99f);
      float w = alpha * T;
      accr = fmaf(w, cr, accr);
      accg = fmaf(w, cg, accg);
      accb = fmaf(w, cb, accb);
      T = fmaf(-alpha, T, T);
    }
  }
  s_part[tid] = make_float4(accr, accg, accb, T);
  __syncthreads();
  if (q == 0) {
    float4 P0 = s_part[p];
    float4 P1 = s_part[p + 256];
    float4 P2 = s_part[p + 512];
    float4 P3 = s_part[p + 768];
    float r = P0.x + P0.w * (P1.x + P1.w * (P2.x + P2.w * P3.x));
    float g = P0.y + P0.w * (P1.y + P1.w * (P2.y + P2.w * P3.y));
    float b = P0.z + P0.w * (P1.z + P1.w * (P2.z + P2.w * P3.z));
    const int row = ty * TILE + prow;
    const int col = tx * TILE + pcol;
    const int o = (row * W + col) * 3;
    out[o+0] = fminf(fmaxf(r, 0.0f), 1.0f);
    out[o+1] = fminf(fmaxf(g, 0.0f), 1.0f);
    out[o+2] = fminf(fmaxf(b, 0.0f), 1.0f);
  }
}

// ---- render from prebuilt segmented lists ----

__global__ __launch_bounds__(BT)
void render_list(const float4* __restrict__ pa, const float4* __restrict__ pb,
                 const float4* __restrict__ pc, const int* __restrict__ seglen,
                 const unsigned long long* __restrict__ listd,
                 const unsigned long long* __restrict__ listz,
                 float* __restrict__ out, int nb) {
  __shared__ unsigned long long s_zkey[CAP];
  __shared__ unsigned long long s_dkey[CAP];
  __shared__ int s_off[NB_MAX + 1];
  __shared__ int s_rank[K];
  __shared__ float4 s_q0[K];
  __shared__ float4 s_q1[K];
  __shared__ float  s_q2[K];
  __shared__ float4 s_part[BT];

  const int t  = (int)blockIdx.x;
  const int tx = t % NTX;
  const int ty = t / NTX;
  const int tid = (int)threadIdx.x;

  if (tid < K) s_rank[tid] = 0;
  if (tid < 64) {
    int v = (tid < nb) ? seglen[(size_t)t * NB_MAX + tid] : 0;
    #pragma unroll
    for (int d = 1; d < 64; d <<= 1) {
      int u2 = __shfl_up(v, d, 64);
      if (tid >= d) v += u2;
    }
    if (tid == 0) s_off[0] = 0;
    if (tid < nb) s_off[tid + 1] = v;
  }
  __syncthreads();
  int cnt = min(s_off[nb], CAP);

  // gather z-keys only (dist keys gathered lazily on the rare cnt>K path)
  for (int i = tid; i < cnt; i += BT) {
    int lo = 0, hi = nb;
    while (hi - lo > 1) {
      int mid = (lo + hi) >> 1;
      if (s_off[mid] <= i) lo = mid; else hi = mid;
    }
    size_t src = ((size_t)t * NB_MAX + lo) * SEG + (size_t)(i - s_off[lo]);
    s_zkey[i] = listz[src];
  }
  __syncthreads();
  int cnt2 = cnt;

  if (cnt > K) {
    // exact top-K by (dist, idx) ascending == top_k on -dist
    for (int i = tid; i < cnt; i += BT) {
      int lo = 0, hi = nb;
      while (hi - lo > 1) {
        int mid = (lo + hi) >> 1;
        if (s_off[mid] <= i) lo = mid; else hi = mid;
      }
      size_t src = ((size_t)t * NB_MAX + lo) * SEG + (size_t)(i - s_off[lo]);
      s_dkey[i] = listd[src];
    }
    int M = 512; while (M < cnt) M <<= 1;
    for (int i = cnt + tid; i < M; i += BT) s_dkey[i] = ~0ull;
    hsort1(s_dkey, M);
    if (tid < K) {
      int g = (int)(s_dkey[tid] & 0xffffffffu);
      s_zkey[tid] = ((unsigned long long)__float_as_uint(pa[g].w) << 32) |
                    (unsigned int)g;
    }
    __syncthreads();
    cnt2 = K;
  }

  tail_blend(pa, pb, pc, out, s_zkey, s_rank, s_q0, s_q1, s_q2, s_part,
             cnt2, tx, ty);
}

// ---- fallback: scan render (used only if ws too small) ----

__global__ __launch_bounds__(BT)
void render_scan(const float4* __restrict__ pa, const float4* __restrict__ pb,
                 const float4* __restrict__ pc, float* __restrict__ out, int n) {
  __shared__ unsigned long long s_zkey[CAP];
  __shared__ unsigned long long s_dkey[CAP];
  __shared__ int s_rank[K];
  __shared__ float4 s_q0[K];
  __shared__ float4 s_q1[K];
  __shared__ float  s_q2[K];
  __shared__ float4 s_part[BT];
  __shared__ int s_cnt;

  const int t  = (int)blockIdx.x;
  const int tx = t % NTX;
  const int ty = t / NTX;
  const int tid = (int)threadIdx.x;
  const int lane = tid & 63;
  const float cxc = (tx * TILE + TILE * 0.5f - W * 0.5f) / FX;
  const float cyc = (ty * TILE + TILE * 0.5f - H * 0.5f) / FY;

  if (tid == 0) s_cnt = 0;
  if (tid < K) s_rank[tid] = 0;
  __syncthreads();

  for (int g = tid; g < n; g += BT) {
    float4 v = pa[g];
    float ddx = cxc - v.x, ddy = cyc - v.y;
    float dist = sqrtf(ddx * ddx + ddy * ddy);
    bool hit = (v.z >= 0.0f) && (dist <= v.z);
    unsigned long long m = __ballot(hit);
    if (m) {
      int leader = __ffsll((long long)m) - 1;
      int base = 0;
      if (lane == leader) base = atomicAdd(&s_cnt, __popcll(m));
      base = __shfl(base, leader, 64);
      if (hit) {
        int slot = base + __popcll(m & ((1ull << lane) - 1ull));
        if (slot < CAP) {
          s_dkey[slot] = ((unsigned long long)__float_as_uint(dist) << 32) |
                         (unsigned int)g;
          s_zkey[slot] = ((unsigned long long)__float_as_uint(v.w) << 32) |
                         (unsigned int)g;
        }
      }
    }
  }
  __syncthreads();
  int cnt = min(s_cnt, CAP);
  int cnt2 = cnt;

  if (cnt > K) {
    int M = 512; while (M < cnt) M <<= 1;
    for (int i = cnt + tid; i < M; i += BT) s_dkey[i] = ~0ull;
    hsort1(s_dkey, M);
    if (tid < K) {
      int g = (int)(s_dkey[tid] & 0xffffffffu);
      s_zkey[tid] = ((unsigned long long)__float_as_uint(pa[g].w) << 32) |
                    (unsigned int)g;
    }
    __syncthreads();
    cnt2 = K;
  }

  tail_blend(pa, pb, pc, out, s_zkey, s_rank, s_q0, s_q1, s_q2, s_part,
             cnt2, tx, ty);
}

extern "C" void kernel_launch(void* const* d_in, const int* in_sizes, int n_in,
                              void* d_out, int out_size, void* d_ws, size_t ws_size,
                              hipStream_t stream) {
  const float* pos  = (const float*)d_in[0];
  const float* rgb  = (const float*)d_in[1];
  const float* opac = (const float*)d_in[2];
  const float* quat = (const float*)d_in[3];
  const float* scl  = (const float*)d_in[4];
  const float* w2cr = (const float*)d_in[5];
  const float* w2ct = (const float*)d_in[6];
  float* out = (float*)d_out;
  const int n = in_sizes[0] / 3;
  const int nb = (n + 255) / 256;

  char* ws = (char*)d_ws;
  float4* pa = (float4*)(ws + A_OFF);
  float4* pb = (float4*)(ws + B_OFF);
  float4* pc = (float4*)(ws + C_OFF);
  int* seglen = (int*)(ws + SL_OFF);
  unsigned long long* listd = (unsigned long long*)(ws + LD_OFF);
  unsigned long long* listz = (unsigned long long*)(ws + LZ_OFF);

  if (ws_size >= WS_FULL && nb <= NB_MAX) {
    pre_bin<true><<<nb, 256, 0, stream>>>(
        pos, rgb, opac, quat, scl, w2cr, w2ct, pa, pb, pc, seglen, listd, listz, n);
    render_list<<<NT, BT, 0, stream>>>(pa, pb, pc, seglen, listd, listz, out, nb);
  } else {
    pre_bin<false><<<nb, 256, 0, stream>>>(
        pos, rgb, opac, quat, scl, w2cr, w2ct, pa, pb, pc, seglen, listd, listz, n);
    render_scan<<<NT, BT, 0, stream>>>(pa, pb, pc, out, n);
  }
}